// Round 1
// baseline (58.505 us; speedup 1.0000x reference)
//
#include <hip/hip_runtime.h>

constexpr int B  = 1024;
constexpr int T  = 8192;
constexpr int C  = 2;
constexpr int MS = 128;

// One block per batch row. 4 waves; wave w handles segments m = w, w+4, ...
// Each valid segment [s,e) is summed by the wave's 64 lanes with float2 loads
// (channels are contiguous), then reduced. Lane 0 computes the 2-class NLL.
// Per-row (nll_sum, valid_count) written to partial[b*2 .. b*2+1].
__global__ __launch_bounds__(256) void seg_loss_kernel(
    const float* __restrict__ logits,   // [B, T, C]
    const int*   __restrict__ labels,   // [B, MS]
    const int*   __restrict__ bnd,      // [B, MS, 2]
    float*       __restrict__ partial)  // [B, 2]
{
    const int b    = blockIdx.x;
    const int tid  = threadIdx.x;
    const int lane = tid & 63;
    const int wave = tid >> 6;

    __shared__ float s_nll[4];
    __shared__ float s_cnt[4];

    const float* row = logits + (size_t)b * T * C;

    float wnll = 0.f;
    float wcnt = 0.f;

    for (int m = wave; m < MS; m += 4) {
        const size_t bm = (size_t)b * MS + m;
        int s = bnd[bm * 2 + 0];
        int e = bnd[bm * 2 + 1];
        if (s == -1) continue;                 // invalid segment
        int sc = min(max(s, 0), T);
        int ec = min(max(e, 0), T);

        float sum0 = 0.f, sum1 = 0.f;
        for (int t = sc + lane; t < ec; t += 64) {
            float2 v = *reinterpret_cast<const float2*>(row + (size_t)t * 2);
            sum0 += v.x;
            sum1 += v.y;
        }
        // wave-64 butterfly reduce (deterministic fixed order)
        #pragma unroll
        for (int off = 32; off > 0; off >>= 1) {
            sum0 += __shfl_down(sum0, off, 64);
            sum1 += __shfl_down(sum1, off, 64);
        }

        if (lane == 0) {
            const int len = ec - sc;
            float p0 = 0.f, p1 = 0.f;
            if (len > 0) {
                const float inv = 1.0f / (float)len;
                p0 = sum0 * inv;
                p1 = sum1 * inv;
            }
            const float mx  = fmaxf(p0, p1);
            const float lse = mx + logf(expf(p0 - mx) + expf(p1 - mx));
            const int   lab = labels[bm];
            const float pl  = (lab == 0) ? p0 : p1;
            wnll += lse - pl;
            wcnt += 1.0f;
        }
    }

    if (lane == 0) { s_nll[wave] = wnll; s_cnt[wave] = wcnt; }
    __syncthreads();
    if (tid == 0) {
        partial[(size_t)b * 2 + 0] = s_nll[0] + s_nll[1] + s_nll[2] + s_nll[3];
        partial[(size_t)b * 2 + 1] = s_cnt[0] + s_cnt[1] + s_cnt[2] + s_cnt[3];
    }
}

// Single-block finalize: BCE over B ranking logits + reduce per-row partials.
__global__ __launch_bounds__(256) void finalize_kernel(
    const float* __restrict__ rlogits,  // [B]
    const float* __restrict__ rlabels,  // [B]
    const float* __restrict__ partial,  // [B, 2]
    float*       __restrict__ out)      // [1]
{
    const int tid = threadIdx.x;

    float bce = 0.f;
    for (int i = tid; i < B; i += 256) {
        const float x = rlogits[i];
        const float y = rlabels[i];
        // softplus(x) = max(x,0) + log1p(exp(-|x|))  (stable)
        const float t     = log1pf(expf(-fabsf(x)));
        const float sp_px = fmaxf(x, 0.f) + t;   // softplus(x)
        const float sp_nx = fmaxf(-x, 0.f) + t;  // softplus(-x)
        bce += y * sp_nx + (1.f - y) * sp_px;
    }

    float nll = 0.f, cnt = 0.f;
    for (int i = tid; i < B; i += 256) {
        nll += partial[(size_t)i * 2 + 0];
        cnt += partial[(size_t)i * 2 + 1];
    }

    __shared__ float sb[256], sn[256], sc[256];
    sb[tid] = bce; sn[tid] = nll; sc[tid] = cnt;
    __syncthreads();
    #pragma unroll
    for (int off = 128; off > 0; off >>= 1) {
        if (tid < off) {
            sb[tid] += sb[tid + off];
            sn[tid] += sn[tid + off];
            sc[tid] += sc[tid + off];
        }
        __syncthreads();
    }

    if (tid == 0) {
        const float rank  = sb[0] / (float)B;
        const float prune = (sc[0] > 0.f) ? (sn[0] / sc[0]) : 0.f;
        out[0] = 1.0f * rank + 0.5f * prune;
    }
}

extern "C" void kernel_launch(void* const* d_in, const int* in_sizes, int n_in,
                              void* d_out, int out_size, void* d_ws, size_t ws_size,
                              hipStream_t stream) {
    const float* rlogits = (const float*)d_in[0];  // ranking_logits [B]
    const float* rlabels = (const float*)d_in[1];  // ranking_labels [B]
    const float* plogits = (const float*)d_in[2];  // pruning_logits [B,T,C]
    const int*   plabels = (const int*)  d_in[3];  // pruning_labels [B,MS]
    const int*   bnd     = (const int*)  d_in[4];  // boundaries [B,MS,2]

    float* out     = (float*)d_out;
    float* partial = (float*)d_ws;  // B*2 floats, fully written by kernel 1

    seg_loss_kernel<<<B, 256, 0, stream>>>(plogits, plabels, bnd, partial);
    finalize_kernel<<<1, 256, 0, stream>>>(rlogits, rlabels, partial, out);
}

// Round 2
// 34.691 us; speedup vs baseline: 1.6865x; 1.6865x over previous
//
#include <hip/hip_runtime.h>

constexpr int B   = 1024;
constexpr int T   = 8192;
constexpr int C   = 2;
constexpr int MS  = 128;
constexpr int CHK = 32;        // t-elements per chunk (one chunk per thread)
constexpr int NCH = T / CHK;   // 256 chunks per row

// One block (256 threads) per batch row.
// Phase 1: per-thread contiguous chunk sums (16 x float4 loads).
// Phase 2: LDS Hillis-Steele scan -> exclusive chunk prefix E[0..256].
// Phase 3: 128 threads assemble their segment sum from the prefix with
//          <=31-element edge corrections (cache hits), compute NLL in parallel.
// Phase 4: fixed-order LDS tree reduce -> partial[b] = (nll_sum, valid_count).
__global__ __launch_bounds__(256) void seg_loss_kernel(
    const float* __restrict__ logits,   // [B, T, C]
    const int*   __restrict__ labels,   // [B, MS]
    const int*   __restrict__ bnd,      // [B, MS, 2]
    float*       __restrict__ partial)  // [B, 2]
{
    const int b   = blockIdx.x;
    const int tid = threadIdx.x;
    const float* row = logits + (size_t)b * T * C;

    __shared__ float t0[NCH], t1[NCH];
    __shared__ float e0[NCH + 1], e1[NCH + 1];

    // ---- Phase 1: chunk sums (thread tid owns t in [tid*32, tid*32+32)) ----
    float s0 = 0.f, s1 = 0.f;
    {
        const float4* p = reinterpret_cast<const float4*>(row + (size_t)tid * CHK * C);
        #pragma unroll
        for (int j = 0; j < CHK * C / 4; ++j) {   // 16 float4 = 32 t's
            float4 v = p[j];
            s0 += v.x + v.z;
            s1 += v.y + v.w;
        }
    }

    // ---- Phase 2: inclusive scan over 256 chunk sums -> exclusive E ----
    t0[tid] = s0; t1[tid] = s1;
    __syncthreads();
    #pragma unroll
    for (int off = 1; off < NCH; off <<= 1) {
        float a0 = (tid >= off) ? t0[tid - off] : 0.f;
        float a1 = (tid >= off) ? t1[tid - off] : 0.f;
        __syncthreads();
        t0[tid] += a0; t1[tid] += a1;
        __syncthreads();
    }
    e0[tid + 1] = t0[tid];
    e1[tid + 1] = t1[tid];
    if (tid == 0) { e0[0] = 0.f; e1[0] = 0.f; }
    __syncthreads();

    // ---- Phase 3: per-segment NLL (fully parallel over 128 segments) ----
    float nll = 0.f, cnt = 0.f;
    if (tid < MS) {
        const size_t bm = (size_t)b * MS + tid;
        const int s = bnd[bm * 2 + 0];
        const int e = bnd[bm * 2 + 1];
        if (s != -1) {
            const int sc = min(max(s, 0), T);
            const int ec = min(max(e, 0), T);
            const int cs = sc >> 5;   // CHK = 32
            const int ce = ec >> 5;

            float q0 = e0[ce] - e0[cs];
            float q1 = e1[ce] - e1[cs];
            // head correction: subtract [cs*32, sc)
            for (int t = (cs << 5); t < sc; ++t) {
                float2 v = *reinterpret_cast<const float2*>(row + (size_t)t * 2);
                q0 -= v.x; q1 -= v.y;
            }
            // tail correction: add [ce*32, ec)
            for (int t = (ce << 5); t < ec; ++t) {
                float2 v = *reinterpret_cast<const float2*>(row + (size_t)t * 2);
                q0 += v.x; q1 += v.y;
            }

            const int len = ec - sc;
            float p0 = 0.f, p1 = 0.f;
            if (len > 0) {
                const float inv = 1.0f / (float)len;
                p0 = q0 * inv;
                p1 = q1 * inv;
            }
            const float mx  = fmaxf(p0, p1);
            const float lse = mx + logf(expf(p0 - mx) + expf(p1 - mx));
            const int   lab = labels[bm];
            nll = lse - ((lab == 0) ? p0 : p1);
            cnt = 1.0f;
        }
    }

    // ---- Phase 4: fixed-order block reduce of (nll, cnt) ----
    __shared__ float rn[256], rc[256];
    rn[tid] = nll; rc[tid] = cnt;
    __syncthreads();
    #pragma unroll
    for (int off = 128; off > 0; off >>= 1) {
        if (tid < off) {
            rn[tid] += rn[tid + off];
            rc[tid] += rc[tid + off];
        }
        __syncthreads();
    }
    if (tid == 0) {
        partial[(size_t)b * 2 + 0] = rn[0];
        partial[(size_t)b * 2 + 1] = rc[0];
    }
}

// Single-block finalize: BCE over B ranking logits + reduce per-row partials.
__global__ __launch_bounds__(256) void finalize_kernel(
    const float* __restrict__ rlogits,  // [B]
    const float* __restrict__ rlabels,  // [B]
    const float* __restrict__ partial,  // [B, 2]
    float*       __restrict__ out)      // [1]
{
    const int tid = threadIdx.x;

    float bce = 0.f;
    for (int i = tid; i < B; i += 256) {
        const float x = rlogits[i];
        const float y = rlabels[i];
        const float t     = log1pf(expf(-fabsf(x)));
        const float sp_px = fmaxf(x, 0.f) + t;   // softplus(x)
        const float sp_nx = fmaxf(-x, 0.f) + t;  // softplus(-x)
        bce += y * sp_nx + (1.f - y) * sp_px;
    }

    float nll = 0.f, cnt = 0.f;
    for (int i = tid; i < B; i += 256) {
        nll += partial[(size_t)i * 2 + 0];
        cnt += partial[(size_t)i * 2 + 1];
    }

    __shared__ float sb[256], sn[256], sc[256];
    sb[tid] = bce; sn[tid] = nll; sc[tid] = cnt;
    __syncthreads();
    #pragma unroll
    for (int off = 128; off > 0; off >>= 1) {
        if (tid < off) {
            sb[tid] += sb[tid + off];
            sn[tid] += sn[tid + off];
            sc[tid] += sc[tid + off];
        }
        __syncthreads();
    }

    if (tid == 0) {
        const float rank  = sb[0] / (float)B;
        const float prune = (sc[0] > 0.f) ? (sn[0] / sc[0]) : 0.f;
        out[0] = 1.0f * rank + 0.5f * prune;
    }
}

extern "C" void kernel_launch(void* const* d_in, const int* in_sizes, int n_in,
                              void* d_out, int out_size, void* d_ws, size_t ws_size,
                              hipStream_t stream) {
    const float* rlogits = (const float*)d_in[0];  // ranking_logits [B]
    const float* rlabels = (const float*)d_in[1];  // ranking_labels [B]
    const float* plogits = (const float*)d_in[2];  // pruning_logits [B,T,C]
    const int*   plabels = (const int*)  d_in[3];  // pruning_labels [B,MS]
    const int*   bnd     = (const int*)  d_in[4];  // boundaries [B,MS,2]

    float* out     = (float*)d_out;
    float* partial = (float*)d_ws;  // B*2 floats, fully written by kernel 1

    seg_loss_kernel<<<B, 256, 0, stream>>>(plogits, plabels, bnd, partial);
    finalize_kernel<<<1, 256, 0, stream>>>(rlogits, rlabels, partial, out);
}

// Round 3
// 29.448 us; speedup vs baseline: 1.9867x; 1.1780x over previous
//
#include <hip/hip_runtime.h>

constexpr int B   = 1024;
constexpr int T   = 8192;
constexpr int MS  = 128;
constexpr int CHK = 32;        // t-elements per chunk (one chunk per thread)
constexpr int NCH = T / CHK;   // 256 chunks per row

// One block (256 threads = 4 waves) per batch row.
// Phase 0: prefetch boundaries/labels into registers.
// Phase 1: per-thread contiguous chunk sums; all 16 float4 loads issued
//          before any accumulation (sched_barrier) for max MLP.
// Phase 2: barrier-light scan: in-wave __shfl_up scan + cross-wave fixup.
// Phase 3: 128 threads assemble segment sums from chunk prefix + <=31-elem
//          edge corrections (L2 hits), compute NLL fully in parallel.
// Phase 4: in-wave butterfly + one LDS hop -> partial[b] = (nll, count).
__global__ __launch_bounds__(256) void seg_loss_kernel(
    const float* __restrict__ logits,   // [B, T, 2]
    const int*   __restrict__ labels,   // [B, MS]
    const int*   __restrict__ bnd,      // [B, MS, 2]
    float*       __restrict__ partial)  // [B, 2]
{
    const int b    = blockIdx.x;
    const int tid  = threadIdx.x;
    const int lane = tid & 63;
    const int wave = tid >> 6;
    const float* row = logits + (size_t)b * T * 2;

    // ---- Phase 0: prefetch segment metadata ----
    int s_ = -1, e_ = -1, lab_ = 0;
    if (tid < MS) {
        const size_t bm = (size_t)b * MS + tid;
        s_   = bnd[bm * 2 + 0];
        e_   = bnd[bm * 2 + 1];
        lab_ = labels[bm];
    }

    // ---- Phase 1: chunk sums with forced in-flight loads ----
    float4 v[16];
    {
        const float4* p = reinterpret_cast<const float4*>(row) + (size_t)tid * 16;
        #pragma unroll
        for (int j = 0; j < 16; ++j) v[j] = p[j];
    }
    __builtin_amdgcn_sched_barrier(0);   // keep all 16 loads issued first
    float s0 = 0.f, s1 = 0.f;
    #pragma unroll
    for (int j = 0; j < 16; ++j) {
        s0 += v[j].x + v[j].z;
        s1 += v[j].y + v[j].w;
    }

    // ---- Phase 2: inclusive scan (in-wave shuffle + cross-wave fixup) ----
    float x0 = s0, x1 = s1;
    #pragma unroll
    for (int off = 1; off < 64; off <<= 1) {
        float y0 = __shfl_up(x0, off, 64);
        float y1 = __shfl_up(x1, off, 64);
        if (lane >= off) { x0 += y0; x1 += y1; }
    }
    __shared__ float wtot0[4], wtot1[4];
    __shared__ float e0[NCH + 1], e1[NCH + 1];
    if (lane == 63) { wtot0[wave] = x0; wtot1[wave] = x1; }
    __syncthreads();
    float pre0 = 0.f, pre1 = 0.f;
    #pragma unroll
    for (int w = 0; w < 3; ++w) {
        if (wave > w) { pre0 += wtot0[w]; pre1 += wtot1[w]; }
    }
    e0[tid + 1] = x0 + pre0;
    e1[tid + 1] = x1 + pre1;
    if (tid == 0) { e0[0] = 0.f; e1[0] = 0.f; }
    __syncthreads();

    // ---- Phase 3: per-segment NLL (parallel over 128 segments) ----
    float nll = 0.f, cnt = 0.f;
    if (tid < MS && s_ != -1) {
        const int sc = min(max(s_, 0), T);
        const int ec = min(max(e_, 0), T);
        const int cs = sc >> 5;   // CHK = 32
        const int ce = ec >> 5;

        float q0 = e0[ce] - e0[cs];
        float q1 = e1[ce] - e1[cs];
        // head correction: subtract [cs*32, sc)
        for (int t = (cs << 5); t < sc; ++t) {
            float2 u = *reinterpret_cast<const float2*>(row + (size_t)t * 2);
            q0 -= u.x; q1 -= u.y;
        }
        // tail correction: add [ce*32, ec)
        for (int t = (ce << 5); t < ec; ++t) {
            float2 u = *reinterpret_cast<const float2*>(row + (size_t)t * 2);
            q0 += u.x; q1 += u.y;
        }

        const int len = ec - sc;
        float p0 = 0.f, p1 = 0.f;
        if (len > 0) {
            const float inv = 1.0f / (float)len;
            p0 = q0 * inv;
            p1 = q1 * inv;
        }
        const float mx  = fmaxf(p0, p1);
        const float lse = mx + logf(expf(p0 - mx) + expf(p1 - mx));
        nll = lse - ((lab_ == 0) ? p0 : p1);
        cnt = 1.0f;
    }

    // ---- Phase 4: in-wave butterfly + one LDS hop ----
    #pragma unroll
    for (int off = 32; off > 0; off >>= 1) {
        nll += __shfl_down(nll, off, 64);
        cnt += __shfl_down(cnt, off, 64);
    }
    __shared__ float rn[4], rc[4];
    if (lane == 0) { rn[wave] = nll; rc[wave] = cnt; }
    __syncthreads();
    if (tid == 0) {
        partial[(size_t)b * 2 + 0] = rn[0] + rn[1] + rn[2] + rn[3];
        partial[(size_t)b * 2 + 1] = rc[0] + rc[1] + rc[2] + rc[3];
    }
}

// Single-block finalize: BCE over B ranking logits + reduce per-row partials.
__global__ __launch_bounds__(256) void finalize_kernel(
    const float* __restrict__ rlogits,  // [B]
    const float* __restrict__ rlabels,  // [B]
    const float* __restrict__ partial,  // [B, 2]
    float*       __restrict__ out)      // [1]
{
    const int tid  = threadIdx.x;
    const int lane = tid & 63;
    const int wave = tid >> 6;

    float bce = 0.f;
    for (int i = tid; i < B; i += 256) {
        const float x = rlogits[i];
        const float y = rlabels[i];
        const float t     = log1pf(expf(-fabsf(x)));
        const float sp_px = fmaxf(x, 0.f) + t;   // softplus(x)
        const float sp_nx = fmaxf(-x, 0.f) + t;  // softplus(-x)
        bce += y * sp_nx + (1.f - y) * sp_px;
    }

    float nll = 0.f, cnt = 0.f;
    for (int i = tid; i < B; i += 256) {
        nll += partial[(size_t)i * 2 + 0];
        cnt += partial[(size_t)i * 2 + 1];
    }

    #pragma unroll
    for (int off = 32; off > 0; off >>= 1) {
        bce += __shfl_down(bce, off, 64);
        nll += __shfl_down(nll, off, 64);
        cnt += __shfl_down(cnt, off, 64);
    }
    __shared__ float sb[4], sn[4], sc[4];
    if (lane == 0) { sb[wave] = bce; sn[wave] = nll; sc[wave] = cnt; }
    __syncthreads();
    if (tid == 0) {
        const float tb = sb[0] + sb[1] + sb[2] + sb[3];
        const float tn = sn[0] + sn[1] + sn[2] + sn[3];
        const float tc = sc[0] + sc[1] + sc[2] + sc[3];
        const float rank  = tb / (float)B;
        const float prune = (tc > 0.f) ? (tn / tc) : 0.f;
        out[0] = 1.0f * rank + 0.5f * prune;
    }
}

extern "C" void kernel_launch(void* const* d_in, const int* in_sizes, int n_in,
                              void* d_out, int out_size, void* d_ws, size_t ws_size,
                              hipStream_t stream) {
    const float* rlogits = (const float*)d_in[0];  // ranking_logits [B]
    const float* rlabels = (const float*)d_in[1];  // ranking_labels [B]
    const float* plogits = (const float*)d_in[2];  // pruning_logits [B,T,C]
    const int*   plabels = (const int*)  d_in[3];  // pruning_labels [B,MS]
    const int*   bnd     = (const int*)  d_in[4];  // boundaries [B,MS,2]

    float* out     = (float*)d_out;
    float* partial = (float*)d_ws;  // B*2 floats, fully written by kernel 1

    seg_loss_kernel<<<B, 256, 0, stream>>>(plogits, plabels, bnd, partial);
    finalize_kernel<<<1, 256, 0, stream>>>(rlogits, rlabels, partial, out);
}